// Round 4
// baseline (480.471 us; speedup 1.0000x reference)
//
#include <hip/hip_runtime.h>
#include <cstddef>

#define N_H 8
#define N_C 32
#define N_HC 256
#define SLOPE 0.2f

// ---------- preprocessing ----------
__global__ __launch_bounds__(256) void pre_x_kernel(const float* __restrict__ x,
                                                    float* __restrict__ xp, int Nn) {
    int i = blockIdx.x * blockDim.x + threadIdx.x;
    if (i >= Nn) return;
    float r[6];
#pragma unroll
    for (int j = 0; j < 6; ++j) r[j] = x[i * 6 + j];
    if (r[2] == 1.0f) r[1] = (r[1] - r[0]) * 0.01f;
#pragma unroll
    for (int j = 0; j < 6; ++j) xp[i * 6 + j] = r[j];
}

__global__ __launch_bounds__(256) void ea_colsum_kernel(const float* __restrict__ ea,
                                                        float* __restrict__ sums, int E) {
    float loc[11];
#pragma unroll
    for (int j = 0; j < 11; ++j) loc[j] = 0.f;
    for (int i = blockIdx.x * blockDim.x + threadIdx.x; i < E; i += gridDim.x * blockDim.x) {
        float r[11];
#pragma unroll
        for (int j = 0; j < 11; ++j) r[j] = ea[i * 11 + j];
        if (r[9] == 1.0f) r[1] = (r[1] - r[0]) * 0.01f;
#pragma unroll
        for (int j = 0; j < 11; ++j) loc[j] += r[j];
    }
    __shared__ float sbuf[256];
#pragma unroll
    for (int j = 0; j < 11; ++j) {
        sbuf[threadIdx.x] = loc[j];
        __syncthreads();
        for (int s = 128; s > 0; s >>= 1) {
            if (threadIdx.x < s) sbuf[threadIdx.x] += sbuf[threadIdx.x + s];
            __syncthreads();
        }
        if (threadIdx.x == 0) atomicAdd(&sums[j], sbuf[0]);
        __syncthreads();
    }
}

__global__ void mean_div_kernel(const float* __restrict__ sums, float* __restrict__ mean, int E) {
    int t = threadIdx.x;
    if (t < 11) mean[t] = sums[t] / (float)E;
}

// ---------- CSR build ----------
__global__ __launch_bounds__(256) void deg_hist_kernel(const int* __restrict__ ei,
                                                       int* __restrict__ deg, int E, int Etot) {
    int e = blockIdx.x * blockDim.x + threadIdx.x;
    if (e >= Etot) return;
    int t = (e < E) ? ei[E + e] : e - E;
    atomicAdd(&deg[t], 1);
}

__global__ __launch_bounds__(1024) void scan_kernel(const int* __restrict__ deg,
                                                    int* __restrict__ offs,
                                                    int* __restrict__ cursor, int Nn) {
    const int T = 1024;
    int tid = threadIdx.x;
    int chunk = (Nn + T - 1) / T;
    int b = tid * chunk;
    int s = 0;
    for (int k = 0; k < chunk; ++k) {
        int i = b + k;
        if (i < Nn) s += deg[i];
    }
    __shared__ int sm[T];
    sm[tid] = s;
    __syncthreads();
    for (int d = 1; d < T; d <<= 1) {
        int v = (tid >= d) ? sm[tid - d] : 0;
        __syncthreads();
        sm[tid] += v;
        __syncthreads();
    }
    int pref = (tid > 0) ? sm[tid - 1] : 0;
    for (int k = 0; k < chunk; ++k) {
        int i = b + k;
        if (i < Nn) {
            offs[i] = pref;
            cursor[i] = pref;
            pref += deg[i];
        }
    }
    if (tid == T - 1) offs[Nn] = sm[T - 1];
}

__global__ __launch_bounds__(256) void scatter_kernel(const int* __restrict__ ei,
                                                      int* __restrict__ cursor,
                                                      int* __restrict__ esrc,
                                                      int* __restrict__ eidx, int E, int Etot) {
    int e = blockIdx.x * blockDim.x + threadIdx.x;
    if (e >= Etot) return;
    int s, t;
    if (e < E) { s = ei[e]; t = ei[E + e]; }
    else       { s = t = e - E; }
    int pos = atomicAdd(&cursor[t], 1);
    esrc[pos] = s;
    eidx[pos] = e;
}

// ---------- layer-0 node transform (K=6) ----------
template <int K, int R>
__global__ __launch_bounds__(256) void node_mm_kernel(const float* __restrict__ X,
                                                      const float* __restrict__ Wl,
                                                      const float* __restrict__ bl,
                                                      const float* __restrict__ Wr,
                                                      const float* __restrict__ br,
                                                      float* __restrict__ xl,
                                                      float* __restrict__ xr, int Nn) {
    __shared__ float xs[R][K];
    int row0 = blockIdx.x * R;
    int tid = threadIdx.x;
    for (int i = tid; i < R * K; i += blockDim.x) {
        int r = i / K, k = i - r * K;
        int gr = row0 + r;
        xs[r][k] = (gr < Nn) ? X[(size_t)gr * K + k] : 0.f;
    }
    __syncthreads();
    int c = tid;
    float accl[R], accr[R];
#pragma unroll
    for (int r = 0; r < R; ++r) { accl[r] = bl[c]; accr[r] = br[c]; }
#pragma unroll
    for (int k = 0; k < K; ++k) {
        float wl = Wl[k * N_HC + c], wr = Wr[k * N_HC + c];
#pragma unroll
        for (int r = 0; r < R; ++r) {
            accl[r] = fmaf(xs[r][k], wl, accl[r]);
            accr[r] = fmaf(xs[r][k], wr, accr[r]);
        }
    }
#pragma unroll
    for (int r = 0; r < R; ++r) {
        int gr = row0 + r;
        if (gr < Nn) {
            xl[(size_t)gr * N_HC + c] = accl[r];
            xr[(size_t)gr * N_HC + c] = accr[r];
        }
    }
}

// ---------- layer-1 node transform: tiled f32 GEMM (K=256) ----------
__global__ __launch_bounds__(256) void gemm256_kernel(const float* __restrict__ X,
                                                      const float* __restrict__ Wl,
                                                      const float* __restrict__ bl,
                                                      const float* __restrict__ Wr,
                                                      const float* __restrict__ br,
                                                      float* __restrict__ xl,
                                                      float* __restrict__ xr, int Nn) {
    __shared__ float As[32][128];
    __shared__ float Bs[32][128];

    const int by = blockIdx.y;
    const float* __restrict__ W = (by < 2) ? Wl : Wr;
    const float* __restrict__ bias = (by < 2) ? bl : br;
    float* __restrict__ dst = (by < 2) ? xl : xr;
    const int cb = (by & 1) * 128;
    const int row0 = blockIdx.x * 128;
    const int tid = threadIdx.x;
    const int tx = tid & 15, ty = tid >> 4;
    const int tx4 = tx * 4, ty4 = ty * 4;

    const int arow = tid & 127;
    const int akh = (tid >> 7) * 16;
    const int bk0 = tid >> 5;
    const int bc4 = (tid & 31) * 4;

    float acc[8][8];
#pragma unroll
    for (int i = 0; i < 8; ++i)
#pragma unroll
        for (int j = 0; j < 8; ++j) acc[i][j] = 0.f;

    const int garow = row0 + arow;
    const bool aval = garow < Nn;
    const float* __restrict__ asrc = X + (size_t)garow * 256 + akh;

    for (int s = 0; s < 256; s += 32) {
        float4 av[4];
#pragma unroll
        for (int q = 0; q < 4; ++q)
            av[q] = aval ? *(const float4*)(asrc + s + q * 4)
                         : float4{0.f, 0.f, 0.f, 0.f};
#pragma unroll
        for (int q = 0; q < 4; ++q) {
            As[akh + q * 4 + 0][arow] = av[q].x;
            As[akh + q * 4 + 1][arow] = av[q].y;
            As[akh + q * 4 + 2][arow] = av[q].z;
            As[akh + q * 4 + 3][arow] = av[q].w;
        }
#pragma unroll
        for (int q = 0; q < 4; ++q) {
            int kr = bk0 + q * 8;
            *(float4*)&Bs[kr][bc4] = *(const float4*)(W + (size_t)(s + kr) * 256 + cb + bc4);
        }
        __syncthreads();
#pragma unroll 8
        for (int k = 0; k < 32; ++k) {
            const float4 a0 = *(const float4*)&As[k][ty4];
            const float4 a1 = *(const float4*)&As[k][64 + ty4];
            const float4 b0 = *(const float4*)&Bs[k][tx4];
            const float4 b1 = *(const float4*)&Bs[k][64 + tx4];
            const float ar[8] = {a0.x, a0.y, a0.z, a0.w, a1.x, a1.y, a1.z, a1.w};
            const float brr[8] = {b0.x, b0.y, b0.z, b0.w, b1.x, b1.y, b1.z, b1.w};
#pragma unroll
            for (int i = 0; i < 8; ++i)
#pragma unroll
                for (int j = 0; j < 8; ++j) acc[i][j] = fmaf(ar[i], brr[j], acc[i][j]);
        }
        __syncthreads();
    }

    const float4 bv0 = *(const float4*)(bias + cb + tx4);
    const float4 bv1 = *(const float4*)(bias + cb + 64 + tx4);
#pragma unroll
    for (int i = 0; i < 8; ++i) {
        int r = row0 + ((i < 4) ? (ty4 + i) : (64 + ty4 + i - 4));
        if (r < Nn) {
            float4 v0 = {acc[i][0] + bv0.x, acc[i][1] + bv0.y, acc[i][2] + bv0.z,
                         acc[i][3] + bv0.w};
            float4 v1 = {acc[i][4] + bv1.x, acc[i][5] + bv1.y, acc[i][6] + bv1.z,
                         acc[i][7] + bv1.w};
            *(float4*)(dst + (size_t)r * N_HC + cb + tx4) = v0;
            *(float4*)(dst + (size_t)r * N_HC + cb + 64 + tx4) = v1;
        }
    }
}

// ---------- online softmax update ----------
__device__ __forceinline__ void online_update(float logit, const float4& xlv, float& m,
                                              float& den, float4& acc) {
    float mn = fmaxf(m, logit);
    float s = __expf(m - mn);
    float w = __expf(logit - mn);
    den = den * s + w;
    acc.x = fmaf(w, xlv.x, acc.x * s);
    acc.y = fmaf(w, xlv.y, acc.y * s);
    acc.z = fmaf(w, xlv.z, acc.z * s);
    acc.w = fmaf(w, xlv.w, acc.w * s);
    m = mn;
}

template <bool L0>
__device__ __forceinline__ float edge_logit(const float4& xlv, const float4& xrv,
                                            const float4* Wreg, float a, const float4& av) {
    float m0 = xlv.x + xrv.x, m1 = xlv.y + xrv.y, m2 = xlv.z + xrv.z, m3 = xlv.w + xrv.w;
    if (L0) {
#pragma unroll
        for (int j = 0; j < 11; ++j) {
            float aj = __shfl(a, j);
            m0 = fmaf(aj, Wreg[j].x, m0);
            m1 = fmaf(aj, Wreg[j].y, m1);
            m2 = fmaf(aj, Wreg[j].z, m2);
            m3 = fmaf(aj, Wreg[j].w, m3);
        }
    }
    m0 = m0 > 0.f ? m0 : SLOPE * m0;
    m1 = m1 > 0.f ? m1 : SLOPE * m1;
    m2 = m2 > 0.f ? m2 : SLOPE * m2;
    m3 = m3 > 0.f ? m3 : SLOPE * m3;
    float p = m0 * av.x + m1 * av.y + m2 * av.z + m3 * av.w;
    p += __shfl_xor(p, 1);
    p += __shfl_xor(p, 2);
    p += __shfl_xor(p, 4);
    return p;
}

// ---------- fused per-node gather: 4-state online softmax + prefetch ----------
template <bool L0>
__global__ __launch_bounds__(256) void node_gather_kernel(
    const int* __restrict__ offs, const int* __restrict__ esrc, const int* __restrict__ eidx,
    const float* __restrict__ ea, const float* __restrict__ mean_ea,
    const float* __restrict__ We, const float* __restrict__ att, const float* __restrict__ xl,
    const float* __restrict__ xr, const float* __restrict__ bias, float* __restrict__ out,
    int Nn, int E) {
    int wid = threadIdx.x >> 6;
    int lane = threadIdx.x & 63;
    int node = blockIdx.x * 4 + wid;
    if (node >= Nn) return;
    int c4 = lane * 4;

    float4 Wreg[11];
    if (L0) {
#pragma unroll
        for (int j = 0; j < 11; ++j) Wreg[j] = *(const float4*)(We + j * N_HC + c4);
    }
    const float4 xrv = *(const float4*)(xr + (size_t)node * N_HC + c4);
    const float4 av = *(const float4*)(att + c4);

    int beg = offs[node], end = offs[node + 1];
    int deg = end - beg;
    int nfull = deg >> 2;

    float m[4], d[4];
    float4 acc[4];
#pragma unroll
    for (int i = 0; i < 4; ++i) {
        m[i] = -INFINITY;
        d[i] = 0.f;
        acc[i] = {0.f, 0.f, 0.f, 0.f};
    }

    int p = beg;
    float4 xb[4];
    float ab[4];
    int eb[4];

    if (nfull > 0) {
#pragma unroll
        for (int i = 0; i < 4; ++i) {
            int s = esrc[p + i];
            xb[i] = *(const float4*)(xl + (size_t)s * N_HC + c4);
        }
        if (L0) {
#pragma unroll
            for (int i = 0; i < 4; ++i) {
                int e = eidx[p + i];
                eb[i] = e;
                float a = 0.f;
                if (lane < 11) a = (e < E) ? ea[(size_t)e * 11 + lane] : mean_ea[lane];
                ab[i] = a;
            }
        }
    }

    for (int b = 0; b < nfull; ++b) {
        float4 xn[4];
        float an[4];
        int en[4];
        if (b + 1 < nfull) {
#pragma unroll
            for (int i = 0; i < 4; ++i) {
                int s = esrc[p + 4 + i];
                xn[i] = *(const float4*)(xl + (size_t)s * N_HC + c4);
            }
            if (L0) {
#pragma unroll
                for (int i = 0; i < 4; ++i) {
                    int e = eidx[p + 4 + i];
                    en[i] = e;
                    float a = 0.f;
                    if (lane < 11) a = (e < E) ? ea[(size_t)e * 11 + lane] : mean_ea[lane];
                    an[i] = a;
                }
            }
        }
        // compute current batch (loads for next batch now in flight)
#pragma unroll
        for (int i = 0; i < 4; ++i) {
            float a = 0.f;
            if (L0) {
                a = ab[i];
                float q0 = __shfl(a, 0), q9 = __shfl(a, 9);
                if (eb[i] < E && lane == 1 && q9 == 1.0f) a = (a - q0) * 0.01f;
            }
            float lg = edge_logit<L0>(xb[i], xrv, Wreg, a, av);
            online_update(lg, xb[i], m[i], d[i], acc[i]);
        }
#pragma unroll
        for (int i = 0; i < 4; ++i) {
            xb[i] = xn[i];
            if (L0) { ab[i] = an[i]; eb[i] = en[i]; }
        }
        p += 4;
    }

    // tail (0..3 edges)
    for (int i = 0; p < end; ++p, ++i) {
        int s = esrc[p];
        const float4 xv = *(const float4*)(xl + (size_t)s * N_HC + c4);
        float a = 0.f;
        if (L0) {
            int e = eidx[p];
            if (lane < 11) a = (e < E) ? ea[(size_t)e * 11 + lane] : mean_ea[lane];
            float q0 = __shfl(a, 0), q9 = __shfl(a, 9);
            if (e < E && lane == 1 && q9 == 1.0f) a = (a - q0) * 0.01f;
        }
        float lg = edge_logit<L0>(xv, xrv, Wreg, a, av);
        online_update(lg, xv, m[i], d[i], acc[i]);
    }

    // merge 4 states
    float mm = fmaxf(fmaxf(m[0], m[1]), fmaxf(m[2], m[3]));
    float den = 0.f;
    float4 acct = {0.f, 0.f, 0.f, 0.f};
#pragma unroll
    for (int i = 0; i < 4; ++i) {
        float s = __expf(m[i] - mm);
        den += d[i] * s;
        acct.x = fmaf(acc[i].x, s, acct.x);
        acct.y = fmaf(acc[i].y, s, acct.y);
        acct.z = fmaf(acc[i].z, s, acct.z);
        acct.w = fmaf(acc[i].w, s, acct.w);
    }

    const float4 bv = *(const float4*)(bias + c4);
    float4 r;
    r.x = acct.x / den + bv.x;
    r.y = acct.y / den + bv.y;
    r.z = acct.z / den + bv.z;
    r.w = acct.w / den + bv.w;
    if (L0) {
        r.x = r.x > 0.f ? r.x : (__expf(r.x) - 1.f);
        r.y = r.y > 0.f ? r.y : (__expf(r.y) - 1.f);
        r.z = r.z > 0.f ? r.z : (__expf(r.z) - 1.f);
        r.w = r.w > 0.f ? r.w : (__expf(r.w) - 1.f);
    }
    *(float4*)(out + (size_t)node * N_HC + c4) = r;
}

extern "C" void kernel_launch(void* const* d_in, const int* in_sizes, int n_in, void* d_out,
                              int out_size, void* d_ws, size_t ws_size, hipStream_t stream) {
    const float* x = (const float*)d_in[0];
    const int* ei = (const int*)d_in[1];
    const float* ea = (const float*)d_in[2];
    const float* Wl0 = (const float*)d_in[3];
    const float* bl0 = (const float*)d_in[4];
    const float* Wr0 = (const float*)d_in[5];
    const float* br0 = (const float*)d_in[6];
    const float* We0 = (const float*)d_in[7];
    const float* att0 = (const float*)d_in[8];
    const float* bias0 = (const float*)d_in[9];
    const float* Wl1 = (const float*)d_in[10];
    const float* bl1 = (const float*)d_in[11];
    const float* Wr1 = (const float*)d_in[12];
    const float* br1 = (const float*)d_in[13];
    const float* att1 = (const float*)d_in[14];
    const float* bias1 = (const float*)d_in[15];
    float* out = (float*)d_out;

    const int Nn = in_sizes[0] / 6;
    const int E = in_sizes[1] / 2;
    const int Etot = E + Nn;

    auto align16 = [](size_t v) { return (v + 15) & ~(size_t)15; };
    float* ws = (float*)d_ws;
    size_t o = 0;
    float* xp = ws + o;    o = align16(o + (size_t)Nn * 6);
    float* xl = ws + o;    o = align16(o + (size_t)Nn * N_HC);
    float* xr = ws + o;    o = align16(o + (size_t)Nn * N_HC);
    float* h = ws + o;     o = align16(o + (size_t)Nn * N_HC);
    float* easum = ws + o; o = align16(o + 16);
    float* mean = ws + o;  o = align16(o + 16);
    int* deg = (int*)(ws + o);    o = align16(o + (size_t)Nn);
    int* offs = (int*)(ws + o);   o = align16(o + (size_t)Nn + 1);
    int* cursor = (int*)(ws + o); o = align16(o + (size_t)Nn);
    int* esrc = (int*)(ws + o);   o = align16(o + (size_t)Etot);
    int* eidx = (int*)(ws + o);   o = align16(o + (size_t)Etot);

    hipMemsetAsync(easum, 0, 16 * sizeof(float), stream);
    hipMemsetAsync(deg, 0, (size_t)Nn * sizeof(int), stream);

    // preprocessing
    pre_x_kernel<<<(Nn + 255) / 256, 256, 0, stream>>>(x, xp, Nn);
    ea_colsum_kernel<<<256, 256, 0, stream>>>(ea, easum, E);
    mean_div_kernel<<<1, 32, 0, stream>>>(easum, mean, E);

    // CSR build (shared across both layers)
    deg_hist_kernel<<<(Etot + 255) / 256, 256, 0, stream>>>(ei, deg, E, Etot);
    scan_kernel<<<1, 1024, 0, stream>>>(deg, offs, cursor, Nn);
    scatter_kernel<<<(Etot + 255) / 256, 256, 0, stream>>>(ei, cursor, esrc, eidx, E, Etot);

    const int gblocks = (Nn + 3) / 4;

    // layer 0
    node_mm_kernel<6, 8><<<(Nn + 7) / 8, 256, 0, stream>>>(xp, Wl0, bl0, Wr0, br0, xl, xr, Nn);
    node_gather_kernel<true><<<gblocks, 256, 0, stream>>>(offs, esrc, eidx, ea, mean, We0, att0,
                                                          xl, xr, bias0, h, Nn, E);

    // layer 1
    dim3 ggrid((Nn + 127) / 128, 4);
    gemm256_kernel<<<ggrid, 256, 0, stream>>>(h, Wl1, bl1, Wr1, br1, xl, xr, Nn);
    node_gather_kernel<false><<<gblocks, 256, 0, stream>>>(offs, esrc, eidx, nullptr, nullptr,
                                                           nullptr, att1, xl, xr, bias1, out, Nn,
                                                           E);
}

// Round 5
// 322.835 us; speedup vs baseline: 1.4883x; 1.4883x over previous
//
#include <hip/hip_runtime.h>
#include <cstddef>

#define N_H 8
#define N_C 32
#define N_HC 256
#define SLOPE 0.2f

// ---------- edge-attr column means ----------
__global__ __launch_bounds__(256) void ea_colsum_kernel(const float* __restrict__ ea,
                                                        float* __restrict__ sums, int E) {
    float loc[11];
#pragma unroll
    for (int j = 0; j < 11; ++j) loc[j] = 0.f;
    for (int i = blockIdx.x * blockDim.x + threadIdx.x; i < E; i += gridDim.x * blockDim.x) {
        float r[11];
#pragma unroll
        for (int j = 0; j < 11; ++j) r[j] = ea[i * 11 + j];
        if (r[9] == 1.0f) r[1] = (r[1] - r[0]) * 0.01f;
#pragma unroll
        for (int j = 0; j < 11; ++j) loc[j] += r[j];
    }
    __shared__ float sbuf[256];
#pragma unroll
    for (int j = 0; j < 11; ++j) {
        sbuf[threadIdx.x] = loc[j];
        __syncthreads();
        for (int s = 128; s > 0; s >>= 1) {
            if (threadIdx.x < s) sbuf[threadIdx.x] += sbuf[threadIdx.x + s];
            __syncthreads();
        }
        if (threadIdx.x == 0) atomicAdd(&sums[j], sbuf[0]);
        __syncthreads();
    }
}

__global__ void mean_div_kernel(const float* __restrict__ sums, float* __restrict__ mean, int E) {
    int t = threadIdx.x;
    if (t < 11) mean[t] = sums[t] / (float)E;
}

// ---------- CSR build ----------
__global__ __launch_bounds__(256) void deg_hist_kernel(const int* __restrict__ ei,
                                                       int* __restrict__ deg, int E, int Etot) {
    int e = blockIdx.x * blockDim.x + threadIdx.x;
    if (e >= Etot) return;
    int t = (e < E) ? ei[E + e] : e - E;
    atomicAdd(&deg[t], 1);
}

__global__ __launch_bounds__(1024) void scan_kernel(const int* __restrict__ deg,
                                                    int* __restrict__ offs,
                                                    int* __restrict__ cursor, int Nn) {
    const int T = 1024;
    int tid = threadIdx.x;
    int chunk = (Nn + T - 1) / T;
    int b = tid * chunk;
    int s = 0;
    for (int k = 0; k < chunk; ++k) {
        int i = b + k;
        if (i < Nn) s += deg[i];
    }
    __shared__ int sm[T];
    sm[tid] = s;
    __syncthreads();
    for (int d = 1; d < T; d <<= 1) {
        int v = (tid >= d) ? sm[tid - d] : 0;
        __syncthreads();
        sm[tid] += v;
        __syncthreads();
    }
    int pref = (tid > 0) ? sm[tid - 1] : 0;
    for (int k = 0; k < chunk; ++k) {
        int i = b + k;
        if (i < Nn) {
            offs[i] = pref;
            cursor[i] = pref;
            pref += deg[i];
        }
    }
    if (tid == T - 1) offs[Nn] = sm[T - 1];
}

// scatter edges into CSR order; also emit preprocessed edge-attr rows (12-float stride)
__global__ __launch_bounds__(256) void scatter_kernel(const int* __restrict__ ei,
                                                      const float* __restrict__ ea,
                                                      const float* __restrict__ mean_ea,
                                                      int* __restrict__ cursor,
                                                      int* __restrict__ esrc,
                                                      float* __restrict__ ea_csr, int E,
                                                      int Etot) {
    int e = blockIdx.x * blockDim.x + threadIdx.x;
    if (e >= Etot) return;
    int s, t;
    if (e < E) { s = ei[e]; t = ei[E + e]; }
    else       { s = t = e - E; }
    int pos = atomicAdd(&cursor[t], 1);
    esrc[pos] = s;
    float r[11];
    if (e < E) {
#pragma unroll
        for (int j = 0; j < 11; ++j) r[j] = ea[(size_t)e * 11 + j];
        if (r[9] == 1.0f) r[1] = (r[1] - r[0]) * 0.01f;
    } else {
#pragma unroll
        for (int j = 0; j < 11; ++j) r[j] = mean_ea[j];
    }
    float* dst = ea_csr + (size_t)pos * 12;
#pragma unroll
    for (int j = 0; j < 11; ++j) dst[j] = r[j];
}

// ---------- layer-0 node transform (K=6), x-preprocessing fused into staging ----------
template <int K, int R>
__global__ __launch_bounds__(256) void node_mm_kernel(const float* __restrict__ X,
                                                      const float* __restrict__ Wl,
                                                      const float* __restrict__ bl,
                                                      const float* __restrict__ Wr,
                                                      const float* __restrict__ br,
                                                      float* __restrict__ xl,
                                                      float* __restrict__ xr, int Nn) {
    __shared__ float xs[R][K];
    int row0 = blockIdx.x * R;
    int tid = threadIdx.x;
    for (int i = tid; i < R * K; i += blockDim.x) {
        int r = i / K, k = i - r * K;
        int gr = row0 + r;
        float v = 0.f;
        if (gr < Nn) {
            v = X[(size_t)gr * K + k];
            if (k == 1) {
                float x0 = X[(size_t)gr * K + 0];
                float x2 = X[(size_t)gr * K + 2];
                if (x2 == 1.0f) v = (v - x0) * 0.01f;
            }
        }
        xs[r][k] = v;
    }
    __syncthreads();
    int c = tid;
    float accl[R], accr[R];
#pragma unroll
    for (int r = 0; r < R; ++r) { accl[r] = bl[c]; accr[r] = br[c]; }
#pragma unroll
    for (int k = 0; k < K; ++k) {
        float wl = Wl[k * N_HC + c], wr = Wr[k * N_HC + c];
#pragma unroll
        for (int r = 0; r < R; ++r) {
            accl[r] = fmaf(xs[r][k], wl, accl[r]);
            accr[r] = fmaf(xs[r][k], wr, accr[r]);
        }
    }
#pragma unroll
    for (int r = 0; r < R; ++r) {
        int gr = row0 + r;
        if (gr < Nn) {
            xl[(size_t)gr * N_HC + c] = accl[r];
            xr[(size_t)gr * N_HC + c] = accr[r];
        }
    }
}

// ---------- layer-1 node transform: tiled f32 GEMM (K=256) ----------
__global__ __launch_bounds__(256) void gemm256_kernel(const float* __restrict__ X,
                                                      const float* __restrict__ Wl,
                                                      const float* __restrict__ bl,
                                                      const float* __restrict__ Wr,
                                                      const float* __restrict__ br,
                                                      float* __restrict__ xl,
                                                      float* __restrict__ xr, int Nn) {
    __shared__ float As[32][128];
    __shared__ float Bs[32][128];

    const int by = blockIdx.y;
    const float* __restrict__ W = (by < 2) ? Wl : Wr;
    const float* __restrict__ bias = (by < 2) ? bl : br;
    float* __restrict__ dst = (by < 2) ? xl : xr;
    const int cb = (by & 1) * 128;
    const int row0 = blockIdx.x * 128;
    const int tid = threadIdx.x;
    const int tx = tid & 15, ty = tid >> 4;
    const int tx4 = tx * 4, ty4 = ty * 4;

    const int arow = tid & 127;
    const int akh = (tid >> 7) * 16;
    const int bk0 = tid >> 5;
    const int bc4 = (tid & 31) * 4;

    float acc[8][8];
#pragma unroll
    for (int i = 0; i < 8; ++i)
#pragma unroll
        for (int j = 0; j < 8; ++j) acc[i][j] = 0.f;

    const int garow = row0 + arow;
    const bool aval = garow < Nn;
    const float* __restrict__ asrc = X + (size_t)garow * 256 + akh;

    for (int s = 0; s < 256; s += 32) {
        float4 av[4];
#pragma unroll
        for (int q = 0; q < 4; ++q)
            av[q] = aval ? *(const float4*)(asrc + s + q * 4)
                         : float4{0.f, 0.f, 0.f, 0.f};
#pragma unroll
        for (int q = 0; q < 4; ++q) {
            As[akh + q * 4 + 0][arow] = av[q].x;
            As[akh + q * 4 + 1][arow] = av[q].y;
            As[akh + q * 4 + 2][arow] = av[q].z;
            As[akh + q * 4 + 3][arow] = av[q].w;
        }
#pragma unroll
        for (int q = 0; q < 4; ++q) {
            int kr = bk0 + q * 8;
            *(float4*)&Bs[kr][bc4] = *(const float4*)(W + (size_t)(s + kr) * 256 + cb + bc4);
        }
        __syncthreads();
#pragma unroll 8
        for (int k = 0; k < 32; ++k) {
            const float4 a0 = *(const float4*)&As[k][ty4];
            const float4 a1 = *(const float4*)&As[k][64 + ty4];
            const float4 b0 = *(const float4*)&Bs[k][tx4];
            const float4 b1 = *(const float4*)&Bs[k][64 + tx4];
            const float ar[8] = {a0.x, a0.y, a0.z, a0.w, a1.x, a1.y, a1.z, a1.w};
            const float brr[8] = {b0.x, b0.y, b0.z, b0.w, b1.x, b1.y, b1.z, b1.w};
#pragma unroll
            for (int i = 0; i < 8; ++i)
#pragma unroll
                for (int j = 0; j < 8; ++j) acc[i][j] = fmaf(ar[i], brr[j], acc[i][j]);
        }
        __syncthreads();
    }

    const float4 bv0 = *(const float4*)(bias + cb + tx4);
    const float4 bv1 = *(const float4*)(bias + cb + 64 + tx4);
#pragma unroll
    for (int i = 0; i < 8; ++i) {
        int r = row0 + ((i < 4) ? (ty4 + i) : (64 + ty4 + i - 4));
        if (r < Nn) {
            float4 v0 = {acc[i][0] + bv0.x, acc[i][1] + bv0.y, acc[i][2] + bv0.z,
                         acc[i][3] + bv0.w};
            float4 v1 = {acc[i][4] + bv1.x, acc[i][5] + bv1.y, acc[i][6] + bv1.z,
                         acc[i][7] + bv1.w};
            *(float4*)(dst + (size_t)r * N_HC + cb + tx4) = v0;
            *(float4*)(dst + (size_t)r * N_HC + cb + 64 + tx4) = v1;
        }
    }
}

// ---------- online softmax update ----------
__device__ __forceinline__ void online_update(float logit, const float4& xlv, float& m,
                                              float& den, float4& acc) {
    float mn = fmaxf(m, logit);
    float s = __expf(m - mn);
    float w = __expf(logit - mn);
    den = den * s + w;
    acc.x = fmaf(w, xlv.x, acc.x * s);
    acc.y = fmaf(w, xlv.y, acc.y * s);
    acc.z = fmaf(w, xlv.z, acc.z * s);
    acc.w = fmaf(w, xlv.w, acc.w * s);
    m = mn;
}

// logit from gathered row; edge-attr comes in via wave-uniform pointer (scalar loads)
template <bool L0>
__device__ __forceinline__ float edge_logit(const float4& xlv, const float4& xrv,
                                            const float4* Wreg, const float* __restrict__ eap,
                                            const float4& av) {
    float m0 = xlv.x + xrv.x, m1 = xlv.y + xrv.y, m2 = xlv.z + xrv.z, m3 = xlv.w + xrv.w;
    if (L0) {
#pragma unroll
        for (int j = 0; j < 11; ++j) {
            float aj = eap[j];
            m0 = fmaf(aj, Wreg[j].x, m0);
            m1 = fmaf(aj, Wreg[j].y, m1);
            m2 = fmaf(aj, Wreg[j].z, m2);
            m3 = fmaf(aj, Wreg[j].w, m3);
        }
    }
    m0 = m0 > 0.f ? m0 : SLOPE * m0;
    m1 = m1 > 0.f ? m1 : SLOPE * m1;
    m2 = m2 > 0.f ? m2 : SLOPE * m2;
    m3 = m3 > 0.f ? m3 : SLOPE * m3;
    float p = m0 * av.x + m1 * av.y + m2 * av.z + m3 * av.w;
    p += __shfl_xor(p, 1);
    p += __shfl_xor(p, 2);
    p += __shfl_xor(p, 4);
    return p;
}

// ---------- fused per-node gather: 4 named states, 4 loads in flight ----------
template <bool L0>
__global__ __launch_bounds__(256) void node_gather_kernel(
    const int* __restrict__ offs, const int* __restrict__ esrc,
    const float* __restrict__ ea_csr, const float* __restrict__ We,
    const float* __restrict__ att, const float* __restrict__ xl, const float* __restrict__ xr,
    const float* __restrict__ bias, float* __restrict__ out, int Nn) {
    int wid = threadIdx.x >> 6;
    int lane = threadIdx.x & 63;
    int node = blockIdx.x * 4 + wid;
    if (node >= Nn) return;
    int c4 = lane * 4;

    float4 Wreg[11];
    if (L0) {
#pragma unroll
        for (int j = 0; j < 11; ++j) Wreg[j] = *(const float4*)(We + j * N_HC + c4);
    }
    const float4 xrv = *(const float4*)(xr + (size_t)node * N_HC + c4);
    const float4 av = *(const float4*)(att + c4);

    int beg = offs[node], end = offs[node + 1];

    float mA = -INFINITY, dA = 0.f;
    float mB = -INFINITY, dB = 0.f;
    float mC = -INFINITY, dC = 0.f;
    float mD = -INFINITY, dD = 0.f;
    float4 aA = {0.f, 0.f, 0.f, 0.f}, aB = aA, aC = aA, aD = aA;

    int p = beg;
    for (; p + 3 < end; p += 4) {
        int pu = __builtin_amdgcn_readfirstlane(p);
        int s0 = esrc[pu + 0];
        int s1 = esrc[pu + 1];
        int s2 = esrc[pu + 2];
        int s3 = esrc[pu + 3];
        const float4 x0 = *(const float4*)(xl + (size_t)s0 * N_HC + c4);
        const float4 x1 = *(const float4*)(xl + (size_t)s1 * N_HC + c4);
        const float4 x2 = *(const float4*)(xl + (size_t)s2 * N_HC + c4);
        const float4 x3 = *(const float4*)(xl + (size_t)s3 * N_HC + c4);
        const float* e0 = L0 ? (ea_csr + (size_t)(pu + 0) * 12) : nullptr;
        const float* e1 = L0 ? (ea_csr + (size_t)(pu + 1) * 12) : nullptr;
        const float* e2 = L0 ? (ea_csr + (size_t)(pu + 2) * 12) : nullptr;
        const float* e3 = L0 ? (ea_csr + (size_t)(pu + 3) * 12) : nullptr;
        float lg0 = edge_logit<L0>(x0, xrv, Wreg, e0, av);
        float lg1 = edge_logit<L0>(x1, xrv, Wreg, e1, av);
        float lg2 = edge_logit<L0>(x2, xrv, Wreg, e2, av);
        float lg3 = edge_logit<L0>(x3, xrv, Wreg, e3, av);
        online_update(lg0, x0, mA, dA, aA);
        online_update(lg1, x1, mB, dB, aB);
        online_update(lg2, x2, mC, dC, aC);
        online_update(lg3, x3, mD, dD, aD);
    }
    for (; p < end; ++p) {
        int pu = __builtin_amdgcn_readfirstlane(p);
        int s0 = esrc[pu];
        const float4 x0 = *(const float4*)(xl + (size_t)s0 * N_HC + c4);
        const float* e0 = L0 ? (ea_csr + (size_t)pu * 12) : nullptr;
        float lg0 = edge_logit<L0>(x0, xrv, Wreg, e0, av);
        online_update(lg0, x0, mA, dA, aA);
    }

    // merge 4 states
    float mm = fmaxf(fmaxf(mA, mB), fmaxf(mC, mD));
    float sA = __expf(mA - mm), sB = __expf(mB - mm);
    float sC = __expf(mC - mm), sD = __expf(mD - mm);
    float den = dA * sA + dB * sB + dC * sC + dD * sD;
    float4 acct;
    acct.x = aA.x * sA + aB.x * sB + aC.x * sC + aD.x * sD;
    acct.y = aA.y * sA + aB.y * sB + aC.y * sC + aD.y * sD;
    acct.z = aA.z * sA + aB.z * sB + aC.z * sC + aD.z * sD;
    acct.w = aA.w * sA + aB.w * sB + aC.w * sC + aD.w * sD;

    const float4 bv = *(const float4*)(bias + c4);
    float4 r;
    r.x = acct.x / den + bv.x;
    r.y = acct.y / den + bv.y;
    r.z = acct.z / den + bv.z;
    r.w = acct.w / den + bv.w;
    if (L0) {
        r.x = r.x > 0.f ? r.x : (__expf(r.x) - 1.f);
        r.y = r.y > 0.f ? r.y : (__expf(r.y) - 1.f);
        r.z = r.z > 0.f ? r.z : (__expf(r.z) - 1.f);
        r.w = r.w > 0.f ? r.w : (__expf(r.w) - 1.f);
    }
    *(float4*)(out + (size_t)node * N_HC + c4) = r;
}

extern "C" void kernel_launch(void* const* d_in, const int* in_sizes, int n_in, void* d_out,
                              int out_size, void* d_ws, size_t ws_size, hipStream_t stream) {
    const float* x = (const float*)d_in[0];
    const int* ei = (const int*)d_in[1];
    const float* ea = (const float*)d_in[2];
    const float* Wl0 = (const float*)d_in[3];
    const float* bl0 = (const float*)d_in[4];
    const float* Wr0 = (const float*)d_in[5];
    const float* br0 = (const float*)d_in[6];
    const float* We0 = (const float*)d_in[7];
    const float* att0 = (const float*)d_in[8];
    const float* bias0 = (const float*)d_in[9];
    const float* Wl1 = (const float*)d_in[10];
    const float* bl1 = (const float*)d_in[11];
    const float* Wr1 = (const float*)d_in[12];
    const float* br1 = (const float*)d_in[13];
    const float* att1 = (const float*)d_in[14];
    const float* bias1 = (const float*)d_in[15];
    float* out = (float*)d_out;

    const int Nn = in_sizes[0] / 6;
    const int E = in_sizes[1] / 2;
    const int Etot = E + Nn;

    auto align16 = [](size_t v) { return (v + 15) & ~(size_t)15; };
    float* ws = (float*)d_ws;
    size_t o = 0;
    float* xl = ws + o;     o = align16(o + (size_t)Nn * N_HC);
    float* xr = ws + o;     o = align16(o + (size_t)Nn * N_HC);
    float* h = ws + o;      o = align16(o + (size_t)Nn * N_HC);
    float* ea_csr = ws + o; o = align16(o + (size_t)Etot * 12);
    float* easum = ws + o;  o = align16(o + 16);
    float* mean = ws + o;   o = align16(o + 16);
    int* deg = (int*)(ws + o);    o = align16(o + (size_t)Nn);
    int* offs = (int*)(ws + o);   o = align16(o + (size_t)Nn + 1);
    int* cursor = (int*)(ws + o); o = align16(o + (size_t)Nn);
    int* esrc = (int*)(ws + o);   o = align16(o + (size_t)Etot);

    hipMemsetAsync(easum, 0, 16 * sizeof(float), stream);
    hipMemsetAsync(deg, 0, (size_t)Nn * sizeof(int), stream);

    // edge-attr mean (preprocessed)
    ea_colsum_kernel<<<256, 256, 0, stream>>>(ea, easum, E);
    mean_div_kernel<<<1, 32, 0, stream>>>(easum, mean, E);

    // CSR build (shared across both layers) + preprocessed edge-attr in CSR order
    deg_hist_kernel<<<(Etot + 255) / 256, 256, 0, stream>>>(ei, deg, E, Etot);
    scan_kernel<<<1, 1024, 0, stream>>>(deg, offs, cursor, Nn);
    scatter_kernel<<<(Etot + 255) / 256, 256, 0, stream>>>(ei, ea, mean, cursor, esrc, ea_csr, E,
                                                           Etot);

    const int gblocks = (Nn + 3) / 4;

    // layer 0
    node_mm_kernel<6, 8><<<(Nn + 7) / 8, 256, 0, stream>>>(x, Wl0, bl0, Wr0, br0, xl, xr, Nn);
    node_gather_kernel<true><<<gblocks, 256, 0, stream>>>(offs, esrc, ea_csr, We0, att0, xl, xr,
                                                          bias0, h, Nn);

    // layer 1
    dim3 ggrid((Nn + 127) / 128, 4);
    gemm256_kernel<<<ggrid, 256, 0, stream>>>(h, Wl1, bl1, Wr1, br1, xl, xr, Nn);
    node_gather_kernel<false><<<gblocks, 256, 0, stream>>>(offs, esrc, nullptr, nullptr, att1, xl,
                                                           xr, bias1, out, Nn);
}